// Round 7
// baseline (198.098 us; speedup 1.0000x reference)
//
#include <hip/hip_runtime.h>

// 3-NN IDW upsampling, round 7: single fused kernel.
// Each block (256 thr) rebuilds the sparse 16^3 grid in its own LDS
// (packed-u16 hist -> block scan -> scatter), then answers 64 queries with
// 4 lanes/query: Chebyshev shells, contiguous row-segment probes, shared
// prune bound via shfl-min of the 4 lanes' 3rd-best truncated keys.
// Top-6 packed keys per lane -> 24 candidates -> exact-f64 re-rank + f64 IDW
// (epilogue arithmetic identical to rounds 1-6; absmax 0.00390625).

constexpr int   B  = 2;
constexpr int   S  = 4096;
constexpr int   NQ = 16384;
constexpr int   G  = 16;
constexpr int   NC = G * G * G;
constexpr float LOF  = -4.25f;
constexpr float W    = 0.53125f;          // 8.5 / 16
constexpr float INVW = 1.0f / W;

constexpr int THREADS = 256;
constexpr int QPB     = 64;               // queries per block (4 lanes each)
constexpr int PPT     = S / THREADS;      // 16 sparse points per thread (build)

__device__ __forceinline__ unsigned med3u(unsigned a, unsigned b, unsigned c) {
    unsigned d;
    asm("v_med3_u32 %0, %1, %2, %3" : "=v"(d) : "v"(a), "v"(b), "v"(c));
    return d;
}
__device__ __forceinline__ int cell1(float v) {
    int c = (int)floorf((v - LOF) * INVW);
    return min(max(c, 0), G - 1);
}

__global__ __launch_bounds__(THREADS)
void k_knn(const float* __restrict__ xyz, const float* __restrict__ sxyz,
           const float* __restrict__ sflow, float* __restrict__ out)
{
    __shared__ float px[S], py[S], pz[S];            // 48 KiB cell-sorted coords
    __shared__ unsigned short pfx16[NC + 1];         // 8.2 KiB cell prefix
    __shared__ unsigned short sidx[S];               // 8 KiB sorted->orig index
    __shared__ unsigned scratch[2048];               // build: packed u16 cnt/cur
                                                     // epilogue: kbuf[64][25]
    __shared__ unsigned wtot[4];

    const int t   = threadIdx.x;
    const int blk = blockIdx.x;                      // 0..511
    const int b   = blk >> 8;
    const int qb  = blk & 255;

    // ================= build (redundant per block; inputs L2-hot) ==========
    const float* sxb = sxyz + (size_t)b * 3 * S;
    float xx[PPT], yy[PPT], zz[PPT];
    {
        const float4* vx = reinterpret_cast<const float4*>(sxb + t * PPT);
        const float4* vy = reinterpret_cast<const float4*>(sxb + S + t * PPT);
        const float4* vz = reinterpret_cast<const float4*>(sxb + 2 * S + t * PPT);
        #pragma unroll
        for (int k = 0; k < PPT / 4; ++k) {
            const float4 a = vx[k], c = vy[k], d = vz[k];
            xx[4*k+0]=a.x; xx[4*k+1]=a.y; xx[4*k+2]=a.z; xx[4*k+3]=a.w;
            yy[4*k+0]=c.x; yy[4*k+1]=c.y; yy[4*k+2]=c.z; yy[4*k+3]=c.w;
            zz[4*k+0]=d.x; zz[4*k+1]=d.y; zz[4*k+2]=d.z; zz[4*k+3]=d.w;
        }
    }
    #pragma unroll
    for (int k = 0; k < 8; ++k) scratch[t * 8 + k] = 0u;   // zero counters
    __syncthreads();

    #pragma unroll
    for (int k = 0; k < PPT; ++k) {                  // histogram (packed u16)
        const int ci = (cell1(zz[k]) * G + cell1(yy[k])) * G + cell1(xx[k]);
        atomicAdd(&scratch[ci >> 1], (ci & 1) ? 0x10000u : 1u);
    }
    __syncthreads();

    {   // exclusive scan of 4096 u16 counts (thread t owns cells 16t..16t+15)
        unsigned c[16];
        #pragma unroll
        for (int k = 0; k < 8; ++k) {
            const unsigned w2 = scratch[t * 8 + k];
            c[2*k] = w2 & 0xFFFFu; c[2*k+1] = w2 >> 16;
        }
        unsigned tsum = 0;
        #pragma unroll
        for (int k = 0; k < 16; ++k) { const unsigned v = c[k]; c[k] = tsum; tsum += v; }
        const int lane = t & 63, w = t >> 6;
        unsigned sc = tsum;                          // inclusive wave scan
        #pragma unroll
        for (int d = 1; d < 64; d <<= 1) {
            const unsigned o = __shfl_up(sc, d, 64);
            if (lane >= d) sc += o;
        }
        if (lane == 63) wtot[w] = sc;
        __syncthreads();
        unsigned wbase = 0;
        #pragma unroll
        for (int k = 0; k < 4; ++k) wbase += (k < w) ? wtot[k] : 0u;
        const unsigned base = wbase + sc - tsum;
        #pragma unroll
        for (int k = 0; k < 16; ++k) pfx16[t * 16 + k] = (unsigned short)(base + c[k]);
        #pragma unroll
        for (int k = 0; k < 8; ++k)                  // cursors = prefix (packed)
            scratch[t * 8 + k] = (base + c[2*k]) | ((base + c[2*k+1]) << 16);
        if (t == 0) pfx16[NC] = (unsigned short)S;
    }
    __syncthreads();

    #pragma unroll
    for (int k = 0; k < PPT; ++k) {                  // scatter
        const int ci = (cell1(zz[k]) * G + cell1(yy[k])) * G + cell1(xx[k]);
        const unsigned old = atomicAdd(&scratch[ci >> 1], (ci & 1) ? 0x10000u : 1u);
        const unsigned pos = (ci & 1) ? (old >> 16) : (old & 0xFFFFu);
        px[pos] = xx[k]; py[pos] = yy[k]; pz[pos] = zz[k];
        sidx[pos] = (unsigned short)(t * PPT + k);
    }
    __syncthreads();

    // ================= query scan: 4 lanes per query =======================
    const int   qid   = t >> 2;                      // 0..63
    const int   split = t & 3;
    const int   q     = qb * QPB + qid;
    const float* xb   = xyz + (size_t)b * 3 * NQ;
    const float qx = xb[q], qy = xb[NQ + q], qz = xb[2 * NQ + q];
    const int hx = cell1(qx), hy = cell1(qy), hz = cell1(qz);

    float mf;   // min signed distance to home-cell faces (validated r5/r6 bound)
    {
        const float lx = LOF + hx * W, ly = LOF + hy * W, lz = LOF + hz * W;
        const float fx = fminf(qx - lx, lx + W - qx);
        const float fy = fminf(qy - ly, ly + W - qy);
        const float fz = fminf(qz - lz, lz + W - qz);
        mf = fminf(fx, fminf(fy, fz));
    }

    unsigned kk0=0xFFFFFFFFu, kk1=0xFFFFFFFFu, kk2=0xFFFFFFFFu,
             kk3=0xFFFFFFFFu, kk4=0xFFFFFFFFu, kk5=0xFFFFFFFFu;

    auto probe = [&](int ci0, int len) {
        const unsigned s0 = pfx16[ci0];
        const unsigned e0 = pfx16[ci0 + len];
        for (unsigned j = s0; j < e0; ++j) {
            const float ddx = qx - px[j];
            const float ddy = qy - py[j];
            const float ddz = qz - pz[j];
            const float d2 = ddx*ddx + ddy*ddy + ddz*ddz;
            const unsigned c = (__float_as_uint(d2) & 0xFFFFF000u) | j;
            kk5 = med3u(kk4, kk5, c);
            kk4 = med3u(kk3, kk4, c);
            kk3 = med3u(kk2, kk3, c);
            kk2 = med3u(kk1, kk2, c);
            kk1 = med3u(kk0, kk1, c);
            kk0 = min(kk0, c);
        }
    };

    int cnt = 0;   // row round-robin counter (identical sequence on all 4 lanes)
    for (int r = 0; r <= G - 1; ++r) {
        if (r > 0) {
            // shared bound: min over 4 lanes of 3rd-best key is a valid
            // upper bound on the union's true d3 (keys round UP via |0xFFF).
            unsigned d3u = kk2;
            d3u = min(d3u, (unsigned)__shfl_xor((int)d3u, 1, 64));
            d3u = min(d3u, (unsigned)__shfl_xor((int)d3u, 2, 64));
            const float db  = fmaxf((float)(r - 1) * W + mf, 0.0f);
            const float d3f = __uint_as_float(d3u | 0xFFFu) * 1.0001f;
            if (db * db > d3f) break;                // NaN while <3 cands: no break
        }
        for (int dz = -r; dz <= r; ++dz) {
            const int cz = hz + dz;
            if (cz < 0 || cz > G - 1) continue;
            const bool zf = (dz == -r) || (dz == r);
            for (int dy = -r; dy <= r; ++dy) {
                const int cy = hy + dy;
                if (cy < 0 || cy > G - 1) continue;
                const int rowb = (cz * G + cy) * G;
                if (zf || dy == -r || dy == r) {     // full row segment
                    if ((cnt++ & 3) == split) {
                        const int x0 = max(hx - r, 0), x1 = min(hx + r, G - 1);
                        probe(rowb + x0, x1 - x0 + 1);
                    }
                } else {                             // two singleton cells
                    const int xl = hx - r, xr = hx + r;
                    if (xl >= 0)    { if ((cnt++ & 3) == split) probe(rowb + xl, 1); }
                    if (xr <= G - 1){ if ((cnt++ & 3) == split) probe(rowb + xr, 1); }
                }
            }
        }
    }

    // publish per-split top-6 (scratch is free: cursors dead after scatter)
    {
        unsigned* kbuf = scratch;
        const int base = qid * 25 + split * 6;       // stride 25: bank-friendly
        kbuf[base+0]=kk0; kbuf[base+1]=kk1; kbuf[base+2]=kk2;
        kbuf[base+3]=kk3; kbuf[base+4]=kk4; kbuf[base+5]=kk5;
    }
    __syncthreads();

    // ================= epilogue: f64 re-rank + IDW (threads 0..63) =========
    if (t < QPB) {
        const int qq = qb * QPB + t;
        const double qxd = (double)xb[qq];
        const double qyd = (double)xb[NQ + qq];
        const double qzd = (double)xb[2 * NQ + qq];

        double e0 = 1e300, e1 = 1e300, e2 = 1e300;
        int    i0 = 0,     i1 = 0,     i2 = 0;
        const unsigned* kbuf = scratch + t * 25;
        #pragma unroll
        for (int c = 0; c < 24; ++c) {
            const unsigned key = kbuf[c];
            if (key == 0xFFFFFFFFu) continue;        // filler
            const int j = (int)(key & 0xFFFu);
            const double dx = qxd - (double)px[j];
            const double dy = qyd - (double)py[j];
            const double dz = qzd - (double)pz[j];
            const double d2 = dx * dx + dy * dy + dz * dz;
            if (d2 < e2) {
                if (d2 < e1) {
                    e2 = e1; i2 = i1;
                    if (d2 < e0) { e1 = e0; i1 = i0; e0 = d2; i0 = j; }
                    else         { e1 = d2; i1 = j; }
                } else {
                    e2 = d2; i2 = j;
                }
            }
        }

        double dist0 = sqrt(e0); dist0 = dist0 > 1e-10 ? dist0 : 1e-10;
        double dist1 = sqrt(e1); dist1 = dist1 > 1e-10 ? dist1 : 1e-10;
        double dist2 = sqrt(e2); dist2 = dist2 > 1e-10 ? dist2 : 1e-10;
        const double inv0 = 1.0 / dist0;
        const double inv1 = 1.0 / dist1;
        const double inv2 = 1.0 / dist2;
        const double wsum = inv0 + inv1 + inv2;

        const int so0 = sidx[i0], so1 = sidx[i1], so2 = sidx[i2];
        const float* fb = sflow + (size_t)b * 3 * S;
        float*       ob = out   + (size_t)b * 3 * NQ;
        #pragma unroll
        for (int c = 0; c < 3; ++c) {
            const float* fc = fb + c * S;
            const double o =
                (inv0 * (double)fc[so0] +
                 inv1 * (double)fc[so1] +
                 inv2 * (double)fc[so2]) / wsum;
            ob[c * NQ + qq] = (float)o;
        }
    }
}

extern "C" void kernel_launch(void* const* d_in, const int* in_sizes, int n_in,
                              void* d_out, int out_size, void* d_ws, size_t ws_size,
                              hipStream_t stream)
{
    const float* xyz  = (const float*)d_in[0];
    const float* sxyz = (const float*)d_in[1];
    const float* sflw = (const float*)d_in[2];
    float*       out  = (float*)d_out;

    const int blocks = (NQ / QPB) * B;     // 512 (2 per CU)
    k_knn<<<blocks, THREADS, 0, stream>>>(xyz, sxyz, sflw, out);
}